// Round 5
// baseline (798.947 us; speedup 1.0000x reference)
//
#include <hip/hip_runtime.h>
#include <math.h>

#define EPSF 1e-5f

constexpr int Sn = 5, Bn = 8, Hin = 512, Win = 512, Cn = 64;
constexpr int HO = 257, WO = 257;
constexpr int HW = HO * WO;           // 66049  (== 1 mod 4)
constexpr int NPIX = Bn * HW;         // 528392
constexpr int TOTPIX = Sn * NPIX;     // 2641960

// Workspace layout per scale (floats):
//   [0,64)          : sorted breakpoints tS[64]
//   [64, 64+64*66*2): alpha/beta as float2 ab[o][r], row stride 66 (r in [0,65))
constexpr int WSF = 64 + Cn * 66 * 2;  // 8512 floats per scale

typedef float f32x4 __attribute__((ext_vector_type(4)));

// ---------------------------------------------------------------------------
// Precompute: piecewise-linear table of the scalar->64ch MLP (unchanged).
// ---------------------------------------------------------------------------
__global__ __launch_bounds__(64) void precompute_kernel(
    const float* __restrict__ w1, const float* __restrict__ w2,
    const float* __restrict__ g1, const float* __restrict__ b1,
    const float* __restrict__ m1, const float* __restrict__ v1,
    const float* __restrict__ g2, const float* __restrict__ b2,
    const float* __restrict__ m2, const float* __restrict__ v2,
    float* __restrict__ ws) {
    int s = blockIdx.x;
    int c = threadIdx.x;
    __shared__ float sa1[Cn], st1[Cn], stc[Cn], stS[Cn];
    __shared__ int   scS[Cn];

    int idx = s * Cn + c;
    float sc1 = g1[idx] / sqrtf(v1[idx] + EPSF);
    float a1  = sc1 * w1[idx];                 // w1 shape (S,C,1)
    float t1  = b1[idx] - m1[idx] * sc1;
    sa1[c] = a1;
    st1[c] = t1;
    float tc = (a1 != 0.f) ? (-t1 / a1) : INFINITY;
    stc[c] = tc;
    __syncthreads();

    int rk = 0;
    for (int c2 = 0; c2 < Cn; c2++) {
        float t = stc[c2];
        rk += (t < tc) || (t == tc && c2 < c);
    }
    stS[rk] = tc;
    scS[rk] = c;
    __syncthreads();

    float* wss = ws + (size_t)s * WSF;
    wss[c] = stS[c];

    int o = c;
    float sc2 = g2[idx] / sqrtf(v2[idx] + EPSF);
    float t2o = b2[idx] - m2[idx] * sc2;
    const float* w2row = w2 + ((size_t)s * Cn + o) * Cn;

    float alpha = 0.f, beta = t2o;
    for (int cc = 0; cc < Cn; cc++) {
        float a = sa1[cc];
        bool act = (a < 0.f) || (a == 0.f && st1[cc] > 0.f);
        if (act) {
            float wf = sc2 * w2row[cc];
            alpha = fmaf(wf, a, alpha);
            beta  = fmaf(wf, st1[cc], beta);
        }
    }
    float2* abrow = (float2*)(wss + Cn);
    abrow[o * 66 + 0] = make_float2(alpha, beta);

    for (int r = 1; r <= Cn; r++) {
        int cc = scS[r - 1];
        float a = sa1[cc];
        if (a != 0.f) {
            float wf = sc2 * w2row[cc];
            float sgn = (a > 0.f) ? 1.f : -1.f;
            alpha = fmaf(sgn * wf, a, alpha);
            beta  = fmaf(sgn * wf, st1[cc], beta);
        }
        abrow[o * 66 + r] = make_float2(alpha, beta);
    }
}

// ---------------------------------------------------------------------------
// Pass 1: DWT -> L, H only (verified v3 path minus table/search/P).
//   L stored cacheable (re-read by pass 2); H nontemporal.
// ---------------------------------------------------------------------------
constexpr int GPT = 4;
constexpr int TPB = 256;
constexpr int PIXPB = TPB * GPT;                  // 1024
constexpr int NCHUNK = (HW + PIXPB - 1) / PIXPB;  // 65

__device__ __forceinline__ float pwl(const float2 ab, float v) {
    return fmaxf(fmaf(ab.x, v, ab.y), 0.f);
}

__device__ __forceinline__ void dwt_lh(
    const float* __restrict__ xb, int i, int j,
    float l0, float l1, float h0, float h1,
    float& Lq, float& Hq) {
    const int r0 = 2 * i - 1, r1 = 2 * i;
    const int c0 = 2 * j - 1, c1 = 2 * j;
    const float x00 = (r0 >= 0 && r0 < Hin && c0 >= 0 ) ? xb[r0 * Win + c0] : 0.f;
    const float x01 = (r0 >= 0 && r0 < Hin && c1 < Win) ? xb[r0 * Win + c1] : 0.f;
    const float x10 = (r1 < Hin && c0 >= 0 )            ? xb[r1 * Win + c0] : 0.f;
    const float x11 = (r1 < Hin && c1 < Win)            ? xb[r1 * Win + c1] : 0.f;
    Lq = l0 * (l0 * x00 + l1 * x01) + l1 * (l0 * x10 + l1 * x11);
    Hq = h0 * (h0 * x00 + h1 * x01) + h1 * (h0 * x10 + h1 * x11);
}

__global__ __launch_bounds__(TPB) void dwt_kernel(
    const float* __restrict__ x,
    const float* __restrict__ lp, const float* __restrict__ hp,
    float* __restrict__ Lout, float* __restrict__ Hout) {
    const int tid = threadIdx.x;
    const int b = blockIdx.y, s = blockIdx.z;

    const float l0 = lp[2 * s], l1 = lp[2 * s + 1];
    const float h0 = hp[2 * s], h1 = hp[2 * s + 1];
    const float* xb = x + (size_t)b * (Hin * Win);

    const int pbase = (blockIdx.x * TPB + tid) * GPT;

    float Lv[GPT + 3];
    float Hv[GPT + 3];

    int i = pbase / WO;
    int j = pbase - i * WO;
    #pragma unroll
    for (int q = 0; q < GPT; ++q) {
        dwt_lh(xb, i, j, l0, l1, h0, h1, Lv[q], Hv[q]);  // fully guarded inside
        if (++j == WO) { j = 0; ++i; }
    }
    // halo from the next lane (bitwise identical to recomputation)
    Lv[4] = __shfl_down(Lv[0], 1, 64);  Hv[4] = __shfl_down(Hv[0], 1, 64);
    Lv[5] = __shfl_down(Lv[1], 1, 64);  Hv[5] = __shfl_down(Hv[1], 1, 64);
    Lv[6] = __shfl_down(Lv[2], 1, 64);  Hv[6] = __shfl_down(Hv[2], 1, 64);
    if ((tid & 63) == 63) {
        #pragma unroll
        for (int q = GPT; q < GPT + 3; ++q) {
            dwt_lh(xb, i, j, l0, l1, h0, h1, Lv[q], Hv[q]);
            if (++j == WO) { j = 0; ++i; }
        }
    }

    const int sb = s * Bn + b;
    const size_t lb = (size_t)sb * HW + pbase;
    const int dlt = (4 - (sb & 3)) & 3;
    const bool fast = (pbase + GPT + 3 <= HW);

    if (fast) {
        f32x4 l4, h4;
        switch (dlt) {
            case 0:  l4 = f32x4{Lv[0], Lv[1], Lv[2], Lv[3]};
                     h4 = f32x4{Hv[0], Hv[1], Hv[2], Hv[3]}; break;
            case 1:  l4 = f32x4{Lv[1], Lv[2], Lv[3], Lv[4]};
                     h4 = f32x4{Hv[1], Hv[2], Hv[3], Hv[4]}; break;
            case 2:  l4 = f32x4{Lv[2], Lv[3], Lv[4], Lv[5]};
                     h4 = f32x4{Hv[2], Hv[3], Hv[4], Hv[5]}; break;
            default: l4 = f32x4{Lv[3], Lv[4], Lv[5], Lv[6]};
                     h4 = f32x4{Hv[3], Hv[4], Hv[5], Hv[6]}; break;
        }
        *(f32x4*)(Lout + lb + dlt) = l4;                       // cacheable: re-read
        __builtin_nontemporal_store(h4, (f32x4*)(Hout + lb + dlt));
        if (pbase == 0) {
            if (dlt > 0) { Lout[lb + 0] = Lv[0]; Hout[lb + 0] = Hv[0]; }
            if (dlt > 1) { Lout[lb + 1] = Lv[1]; Hout[lb + 1] = Hv[1]; }
            if (dlt > 2) { Lout[lb + 2] = Lv[2]; Hout[lb + 2] = Hv[2]; }
        }
    } else {
        #pragma unroll
        for (int q = 0; q < GPT; ++q) {
            if (pbase + q < HW) {
                Lout[lb + q] = Lv[q];
                Hout[lb + q] = Hv[q];
            }
        }
    }
}

// ---------------------------------------------------------------------------
// Pass 2: P writer. grid = (chunk=65 [fastest], ogroup=16, sb=40).
//   Each block: 1024 px of one (s,b) plane x 4 channels -> 4 contiguous 4 KB
//   spans; consecutive blocks extend the SAME planes sequentially (fill-like
//   write stream). LDS = 64 breakpoints + 4 ab rows = 2.4 KB -> high occupancy.
//   delta per channel is compile-time: pl&3 == o&3 (sb*64 == 0 mod 4).
// ---------------------------------------------------------------------------
__global__ __launch_bounds__(TPB) void pstore_kernel(
    const float* __restrict__ Lin,
    const float* __restrict__ ws,
    float* __restrict__ Pout) {
    __shared__ float  stS[Cn];
    __shared__ float2 sab[4 * 66];

    const int tid = threadIdx.x;
    const int og  = blockIdx.y;          // channel group: o = og*4 + c
    const int sb  = blockIdx.z;          // 0..39
    const int s   = sb >> 3;

    const float* wss = ws + (size_t)s * WSF;
    if (tid < Cn) stS[tid] = wss[tid];
    const float2* abg = (const float2*)(wss + Cn) + (size_t)og * 4 * 66;
    for (int t = tid; t < 4 * 66; t += TPB) sab[t] = abg[t];
    __syncthreads();

    const int p4 = (blockIdx.x * TPB + tid) * GPT;
    const float* Lp = Lin + (size_t)sb * HW;

    float Lv[GPT + 3];
    int   lo7[GPT + 3];

    #pragma unroll
    for (int q = 0; q < GPT; ++q) {
        const int px = p4 + q;
        const float Lq = (px < HW) ? Lp[px] : 0.f;
        Lv[q] = Lq;
        int lo = 0, hi = Cn;
        while (lo < hi) {
            const int mid = (lo + hi) >> 1;
            if (stS[mid] < Lq) lo = mid + 1; else hi = mid;
        }
        lo7[q] = lo;
    }
    // halo from lane+1 (bitwise identical); lane 63 computes directly
    Lv[4] = __shfl_down(Lv[0], 1, 64);  lo7[4] = __shfl_down(lo7[0], 1, 64);
    Lv[5] = __shfl_down(Lv[1], 1, 64);  lo7[5] = __shfl_down(lo7[1], 1, 64);
    Lv[6] = __shfl_down(Lv[2], 1, 64);  lo7[6] = __shfl_down(lo7[2], 1, 64);
    if ((tid & 63) == 63) {
        #pragma unroll
        for (int q = GPT; q < GPT + 3; ++q) {
            const int px = p4 + q;
            const float Lq = (px < HW) ? Lp[px] : 0.f;
            Lv[q] = Lq;
            int lo = 0, hi = Cn;
            while (lo < hi) {
                const int mid = (lo + hi) >> 1;
                if (stS[mid] < Lq) lo = mid + 1; else hi = mid;
            }
            lo7[q] = lo;
        }
    }

    float* const Pb = Pout + ((size_t)sb * Cn + (size_t)og * 4) * HW;

    if (p4 + GPT + 3 <= HW) {
        {   // c=0: delta 0, pixels q=0..3
            f32x4 v = f32x4{pwl(sab[0 * 66 + lo7[0]], Lv[0]),
                            pwl(sab[0 * 66 + lo7[1]], Lv[1]),
                            pwl(sab[0 * 66 + lo7[2]], Lv[2]),
                            pwl(sab[0 * 66 + lo7[3]], Lv[3])};
            *(f32x4*)(Pb + p4) = v;
        }
        {   // c=1: delta 3, pixels q=3..6
            f32x4 v = f32x4{pwl(sab[1 * 66 + lo7[3]], Lv[3]),
                            pwl(sab[1 * 66 + lo7[4]], Lv[4]),
                            pwl(sab[1 * 66 + lo7[5]], Lv[5]),
                            pwl(sab[1 * 66 + lo7[6]], Lv[6])};
            *(f32x4*)(Pb + (size_t)HW + p4 + 3) = v;
        }
        {   // c=2: delta 2, pixels q=2..5
            f32x4 v = f32x4{pwl(sab[2 * 66 + lo7[2]], Lv[2]),
                            pwl(sab[2 * 66 + lo7[3]], Lv[3]),
                            pwl(sab[2 * 66 + lo7[4]], Lv[4]),
                            pwl(sab[2 * 66 + lo7[5]], Lv[5])};
            *(f32x4*)(Pb + 2 * (size_t)HW + p4 + 2) = v;
        }
        {   // c=3: delta 1, pixels q=1..4
            f32x4 v = f32x4{pwl(sab[3 * 66 + lo7[1]], Lv[1]),
                            pwl(sab[3 * 66 + lo7[2]], Lv[2]),
                            pwl(sab[3 * 66 + lo7[3]], Lv[3]),
                            pwl(sab[3 * 66 + lo7[4]], Lv[4])};
            *(f32x4*)(Pb + 3 * (size_t)HW + p4 + 1) = v;
        }
        if (p4 == 0) {  // plane-head patch: elements [0, delta_c)
            Pb[1 * (size_t)HW + 0] = pwl(sab[1 * 66 + lo7[0]], Lv[0]);
            Pb[1 * (size_t)HW + 1] = pwl(sab[1 * 66 + lo7[1]], Lv[1]);
            Pb[1 * (size_t)HW + 2] = pwl(sab[1 * 66 + lo7[2]], Lv[2]);
            Pb[2 * (size_t)HW + 0] = pwl(sab[2 * 66 + lo7[0]], Lv[0]);
            Pb[2 * (size_t)HW + 1] = pwl(sab[2 * 66 + lo7[1]], Lv[1]);
            Pb[3 * (size_t)HW + 0] = pwl(sab[3 * 66 + lo7[0]], Lv[0]);
        }
    } else {
        // plane tail: scalar guarded stores (overlaps with fast neighbors
        // store identical bits -> benign)
        #pragma unroll
        for (int q = 0; q < GPT; ++q) {
            const int px = p4 + q;
            if (px >= HW) break;
            const float Lq = Lv[q];
            const int   r  = lo7[q];
            Pb[0 * (size_t)HW + px] = pwl(sab[0 * 66 + r], Lq);
            Pb[1 * (size_t)HW + px] = pwl(sab[1 * 66 + r], Lq);
            Pb[2 * (size_t)HW + px] = pwl(sab[2 * 66 + r], Lq);
            Pb[3 * (size_t)HW + px] = pwl(sab[3 * 66 + r], Lq);
        }
    }
}

extern "C" void kernel_launch(void* const* d_in, const int* in_sizes, int n_in,
                              void* d_out, int out_size, void* d_ws, size_t ws_size,
                              hipStream_t stream) {
    const float* x  = (const float*)d_in[0];
    const float* lp = (const float*)d_in[1];
    const float* hp = (const float*)d_in[2];
    const float* w1 = (const float*)d_in[3];
    const float* w2 = (const float*)d_in[4];
    const float* g1 = (const float*)d_in[5];
    const float* b1 = (const float*)d_in[6];
    const float* m1 = (const float*)d_in[7];
    const float* v1 = (const float*)d_in[8];
    const float* g2 = (const float*)d_in[9];
    const float* b2 = (const float*)d_in[10];
    const float* m2 = (const float*)d_in[11];
    const float* v2 = (const float*)d_in[12];

    float* out  = (float*)d_out;
    float* Lout = out;                  // [5,8,1,257,257]
    float* Hout = out + TOTPIX;         // [5,8,1,257,257]
    float* Pout = out + 2 * TOTPIX;     // [5,8,64,257,257]
    float* ws   = (float*)d_ws;         // 5 * WSF floats = 170 KB

    precompute_kernel<<<Sn, Cn, 0, stream>>>(w1, w2, g1, b1, m1, v1,
                                             g2, b2, m2, v2, ws);

    dim3 grid1(NCHUNK, Bn, Sn);         // 65 x 8 x 5
    dwt_kernel<<<grid1, TPB, 0, stream>>>(x, lp, hp, Lout, Hout);

    dim3 grid2(NCHUNK, Cn / 4, Sn * Bn);  // 65 x 16 x 40 = 41600 blocks
    pstore_kernel<<<grid2, TPB, 0, stream>>>(Lout, ws, Pout);
}

// Round 6
// 736.417 us; speedup vs baseline: 1.0849x; 1.0849x over previous
//
#include <hip/hip_runtime.h>
#include <math.h>

#define EPSF 1e-5f

constexpr int Sn = 5, Bn = 8, Hin = 512, Win = 512, Cn = 64;
constexpr int HO = 257, WO = 257;
constexpr int HW = HO * WO;           // 66049  (== 1 mod 4)
constexpr int NPIX = Bn * HW;         // 528392
constexpr int TOTPIX = Sn * NPIX;     // 2641960
constexpr int NSB = Sn * Bn;          // 40 (s,b) planes of L
constexpr int HWP = (HW + 3) & ~3;    // 66052, padded plane for LR pairs

// Workspace layout (floats):
//   [0, 5*WSF)  : per-scale tables: 64 sorted breakpoints + ab[o][r] float2[64][66]
//   [LR_OFF, +NSB*HWP*2): LR pairs (L, r_as_float) per (sb, px)
constexpr int    WSF    = 64 + Cn * 66 * 2;          // 8512 floats per scale
constexpr size_t LR_OFF = (size_t)Sn * WSF;          // 42560 floats
constexpr unsigned PTOTu = (unsigned)((long)NSB * Cn * HW);  // 169,085,440
constexpr size_t WS_NEED = (LR_OFF + (size_t)NSB * HWP * 2) * 4;  // ~21.3 MB

typedef float f32x4 __attribute__((ext_vector_type(4)));
typedef f32x4 f32x4u __attribute__((aligned(8)));   // 8B-aligned vector loads

// ---------------------------------------------------------------------------
// Precompute: piecewise-linear table of the scalar->64ch MLP (unchanged).
// ---------------------------------------------------------------------------
__global__ __launch_bounds__(64) void precompute_kernel(
    const float* __restrict__ w1, const float* __restrict__ w2,
    const float* __restrict__ g1, const float* __restrict__ b1,
    const float* __restrict__ m1, const float* __restrict__ v1,
    const float* __restrict__ g2, const float* __restrict__ b2,
    const float* __restrict__ m2, const float* __restrict__ v2,
    float* __restrict__ ws) {
    int s = blockIdx.x;
    int c = threadIdx.x;
    __shared__ float sa1[Cn], st1[Cn], stc[Cn], stS[Cn];
    __shared__ int   scS[Cn];

    int idx = s * Cn + c;
    float sc1 = g1[idx] / sqrtf(v1[idx] + EPSF);
    float a1  = sc1 * w1[idx];                 // w1 shape (S,C,1)
    float t1  = b1[idx] - m1[idx] * sc1;
    sa1[c] = a1;
    st1[c] = t1;
    float tc = (a1 != 0.f) ? (-t1 / a1) : INFINITY;
    stc[c] = tc;
    __syncthreads();

    int rk = 0;
    for (int c2 = 0; c2 < Cn; c2++) {
        float t = stc[c2];
        rk += (t < tc) || (t == tc && c2 < c);
    }
    stS[rk] = tc;
    scS[rk] = c;
    __syncthreads();

    float* wss = ws + (size_t)s * WSF;
    wss[c] = stS[c];

    int o = c;
    float sc2 = g2[idx] / sqrtf(v2[idx] + EPSF);
    float t2o = b2[idx] - m2[idx] * sc2;
    const float* w2row = w2 + ((size_t)s * Cn + o) * Cn;

    float alpha = 0.f, beta = t2o;
    for (int cc = 0; cc < Cn; cc++) {
        float a = sa1[cc];
        bool act = (a < 0.f) || (a == 0.f && st1[cc] > 0.f);
        if (act) {
            float wf = sc2 * w2row[cc];
            alpha = fmaf(wf, a, alpha);
            beta  = fmaf(wf, st1[cc], beta);
        }
    }
    float2* abrow = (float2*)(wss + Cn);
    abrow[o * 66 + 0] = make_float2(alpha, beta);

    for (int r = 1; r <= Cn; r++) {
        int cc = scS[r - 1];
        float a = sa1[cc];
        if (a != 0.f) {
            float wf = sc2 * w2row[cc];
            float sgn = (a > 0.f) ? 1.f : -1.f;
            alpha = fmaf(sgn * wf, a, alpha);
            beta  = fmaf(sgn * wf, st1[cc], beta);
        }
        abrow[o * 66 + r] = make_float2(alpha, beta);
    }
}

// ---------------------------------------------------------------------------
// Pass 1: DWT -> L, H outputs; if WITH_LR also binary-search region r per
// pixel and store (L, r) pairs into ws for the flat P pass.
// ---------------------------------------------------------------------------
constexpr int GPT = 4;
constexpr int TPB = 256;
constexpr int PIXPB = TPB * GPT;                  // 1024
constexpr int NCHUNK = (HW + PIXPB - 1) / PIXPB;  // 65

__device__ __forceinline__ float pwl(const float2 ab, float v) {
    return fmaxf(fmaf(ab.x, v, ab.y), 0.f);
}

__device__ __forceinline__ void dwt_lh(
    const float* __restrict__ xb, int i, int j,
    float l0, float l1, float h0, float h1,
    float& Lq, float& Hq) {
    const int r0 = 2 * i - 1, r1 = 2 * i;
    const int c0 = 2 * j - 1, c1 = 2 * j;
    const float x00 = (r0 >= 0 && r0 < Hin && c0 >= 0 ) ? xb[r0 * Win + c0] : 0.f;
    const float x01 = (r0 >= 0 && r0 < Hin && c1 < Win) ? xb[r0 * Win + c1] : 0.f;
    const float x10 = (r1 < Hin && c0 >= 0 )            ? xb[r1 * Win + c0] : 0.f;
    const float x11 = (r1 < Hin && c1 < Win)            ? xb[r1 * Win + c1] : 0.f;
    Lq = l0 * (l0 * x00 + l1 * x01) + l1 * (l0 * x10 + l1 * x11);
    Hq = h0 * (h0 * x00 + h1 * x01) + h1 * (h0 * x10 + h1 * x11);
}

template <bool WITH_LR>
__global__ __launch_bounds__(TPB) void dwt_kernel(
    const float* __restrict__ x,
    const float* __restrict__ lp, const float* __restrict__ hp,
    const float* __restrict__ ws_tab,
    float* __restrict__ Lout, float* __restrict__ Hout,
    float* __restrict__ lrws) {
    __shared__ float stS[Cn];
    const int tid = threadIdx.x;
    const int b = blockIdx.y, s = blockIdx.z;
    if (WITH_LR) {
        if (tid < Cn) stS[tid] = ws_tab[(size_t)s * WSF + tid];
        __syncthreads();
    }

    const float l0 = lp[2 * s], l1 = lp[2 * s + 1];
    const float h0 = hp[2 * s], h1 = hp[2 * s + 1];
    const float* xb = x + (size_t)b * (Hin * Win);

    const int pbase = (blockIdx.x * TPB + tid) * GPT;

    float Lv[GPT + 3];
    float Hv[GPT + 3];
    int   rr[GPT];

    int i = pbase / WO;
    int j = pbase - i * WO;
    #pragma unroll
    for (int q = 0; q < GPT; ++q) {
        dwt_lh(xb, i, j, l0, l1, h0, h1, Lv[q], Hv[q]);  // fully guarded inside
        if (WITH_LR) {
            int lo = 0, hi = Cn;
            while (lo < hi) {
                const int mid = (lo + hi) >> 1;
                if (stS[mid] < Lv[q]) lo = mid + 1; else hi = mid;
            }
            rr[q] = lo;
        }
        if (++j == WO) { j = 0; ++i; }
    }
    // halo from the next lane (bitwise identical to recomputation)
    Lv[4] = __shfl_down(Lv[0], 1, 64);  Hv[4] = __shfl_down(Hv[0], 1, 64);
    Lv[5] = __shfl_down(Lv[1], 1, 64);  Hv[5] = __shfl_down(Hv[1], 1, 64);
    Lv[6] = __shfl_down(Lv[2], 1, 64);  Hv[6] = __shfl_down(Hv[2], 1, 64);
    if ((tid & 63) == 63) {
        #pragma unroll
        for (int q = GPT; q < GPT + 3; ++q) {
            dwt_lh(xb, i, j, l0, l1, h0, h1, Lv[q], Hv[q]);
            if (++j == WO) { j = 0; ++i; }
        }
    }

    const int sb = s * Bn + b;
    const size_t lb = (size_t)sb * HW + pbase;
    const int dlt = (4 - (sb & 3)) & 3;
    const bool fast = (pbase + GPT + 3 <= HW);

    if (fast) {
        f32x4 l4, h4;
        switch (dlt) {
            case 0:  l4 = f32x4{Lv[0], Lv[1], Lv[2], Lv[3]};
                     h4 = f32x4{Hv[0], Hv[1], Hv[2], Hv[3]}; break;
            case 1:  l4 = f32x4{Lv[1], Lv[2], Lv[3], Lv[4]};
                     h4 = f32x4{Hv[1], Hv[2], Hv[3], Hv[4]}; break;
            case 2:  l4 = f32x4{Lv[2], Lv[3], Lv[4], Lv[5]};
                     h4 = f32x4{Hv[2], Hv[3], Hv[4], Hv[5]}; break;
            default: l4 = f32x4{Lv[3], Lv[4], Lv[5], Lv[6]};
                     h4 = f32x4{Hv[3], Hv[4], Hv[5], Hv[6]}; break;
        }
        *(f32x4*)(Lout + lb + dlt) = l4;   // cacheable (fallback pass 2 re-reads)
        __builtin_nontemporal_store(h4, (f32x4*)(Hout + lb + dlt));
        if (pbase == 0) {
            if (dlt > 0) { Lout[lb + 0] = Lv[0]; Hout[lb + 0] = Hv[0]; }
            if (dlt > 1) { Lout[lb + 1] = Lv[1]; Hout[lb + 1] = Hv[1]; }
            if (dlt > 2) { Lout[lb + 2] = Lv[2]; Hout[lb + 2] = Hv[2]; }
        }
    } else {
        #pragma unroll
        for (int q = 0; q < GPT; ++q) {
            if (pbase + q < HW) {
                Lout[lb + q] = Lv[q];
                Hout[lb + q] = Hv[q];
            }
        }
    }

    if (WITH_LR) {
        float2* lr = (float2*)lrws + (size_t)sb * HWP + pbase;
        if (fast) {
            // 16B-aligned: (sb*HWP + pbase) even, *8B => 32B-mult base
            f32x4 p01 = f32x4{Lv[0], (float)rr[0], Lv[1], (float)rr[1]};
            f32x4 p23 = f32x4{Lv[2], (float)rr[2], Lv[3], (float)rr[3]};
            *(f32x4*)(lr)     = p01;
            *(f32x4*)(lr + 2) = p23;
        } else {
            #pragma unroll
            for (int q = 0; q < GPT; ++q) {
                if (pbase + q < HW) lr[q] = make_float2(Lv[q], (float)rr[q]);
            }
        }
    }
}

// ---------------------------------------------------------------------------
// Pass 2 (flat): P written as one contiguous NT ramp — fill-identical pattern.
// Thread owns 4 consecutive elements of flattened P; plane = flat/HW gives
// (sb, o); (L, r) read from ws pairs (L2/L3-resident); table row in LDS.
// Block covers 4096 elements (4 coalesced chunks) -> spans at most 2 planes.
// ---------------------------------------------------------------------------
constexpr int EPB = TPB * 16;                               // 4096 elems/block
constexpr unsigned NBLK2 = (PTOTu + EPB - 1) / EPB;         // 41281

__global__ __launch_bounds__(TPB) void pstore_flat(
    const float* __restrict__ ws_tab,
    const float* __restrict__ lrws,
    float* __restrict__ Pout) {
    __shared__ float2 tabs[2][66];

    const int tid = threadIdx.x;
    const unsigned base = (unsigned)blockIdx.x * (unsigned)EPB;
    const unsigned plane_first = base / (unsigned)HW;
    unsigned lastf = base + (unsigned)(EPB - 1);
    if (lastf >= PTOTu) lastf = PTOTu - 1u;
    const unsigned plane_last = lastf / (unsigned)HW;

    if (tid < 132) {
        const int slot = (tid >= 66);
        const int idx  = slot ? tid - 66 : tid;
        const unsigned pl = slot ? plane_last : plane_first;
        const int s = pl >> 9;            // plane = ((s*8+b)*64 + o)
        const int o = pl & 63;
        const float2* row =
            (const float2*)(ws_tab + (size_t)s * WSF + Cn) + (size_t)o * 66;
        tabs[slot][idx] = row[idx];
    }
    __syncthreads();

    const float2* LR = (const float2*)lrws;

    #pragma unroll
    for (int k = 0; k < 4; ++k) {
        const unsigned flat = base + (unsigned)k * (TPB * 4u) + (unsigned)tid * 4u;
        if (flat >= PTOTu) break;
        const unsigned plane = flat / (unsigned)HW;
        const unsigned px0   = flat - plane * (unsigned)HW;
        const int row = (plane != plane_first);

        if (px0 <= (unsigned)(HW - 4) && flat + 3u < PTOTu) {
            const float2* lr = LR + (size_t)(plane >> 6) * HWP + px0;
            const f32x4u v01 = *(const f32x4u*)(lr);      // (L0,r0,L1,r1)
            const f32x4u v23 = *(const f32x4u*)(lr + 2);  // (L2,r2,L3,r3)
            const float2 ab0 = tabs[row][(int)v01.y];
            const float2 ab1 = tabs[row][(int)v01.w];
            const float2 ab2 = tabs[row][(int)v23.y];
            const float2 ab3 = tabs[row][(int)v23.w];
            f32x4 outv;
            outv.x = pwl(ab0, v01.x);
            outv.y = pwl(ab1, v01.z);
            outv.z = pwl(ab2, v23.x);
            outv.w = pwl(ab3, v23.z);
            __builtin_nontemporal_store(outv, (f32x4*)(Pout + flat));
        } else {
            #pragma unroll
            for (int e = 0; e < 4; ++e) {
                const unsigned fe = flat + (unsigned)e;
                if (fe >= PTOTu) break;
                const unsigned pl = fe / (unsigned)HW;
                const unsigned px = fe - pl * (unsigned)HW;
                const int rw = (pl != plane_first);
                const float2 lrv = LR[(size_t)(pl >> 6) * HWP + px];
                const float2 ab  = tabs[rw][(int)lrv.y];
                Pout[fe] = pwl(ab, lrv.x);
            }
        }
    }
}

// ---------------------------------------------------------------------------
// Fallback pass 2 (verified v5): used only if ws_size < WS_NEED.
// ---------------------------------------------------------------------------
__global__ __launch_bounds__(TPB) void pstore_v5(
    const float* __restrict__ Lin,
    const float* __restrict__ ws,
    float* __restrict__ Pout) {
    __shared__ float  stS[Cn];
    __shared__ float2 sab[4 * 66];

    const int tid = threadIdx.x;
    const int og  = blockIdx.y;
    const int sb  = blockIdx.z;
    const int s   = sb >> 3;

    const float* wss = ws + (size_t)s * WSF;
    if (tid < Cn) stS[tid] = wss[tid];
    const float2* abg = (const float2*)(wss + Cn) + (size_t)og * 4 * 66;
    for (int t = tid; t < 4 * 66; t += TPB) sab[t] = abg[t];
    __syncthreads();

    const int p4 = (blockIdx.x * TPB + tid) * GPT;
    const float* Lp = Lin + (size_t)sb * HW;

    float Lv[GPT + 3];
    int   lo7[GPT + 3];

    #pragma unroll
    for (int q = 0; q < GPT; ++q) {
        const int px = p4 + q;
        const float Lq = (px < HW) ? Lp[px] : 0.f;
        Lv[q] = Lq;
        int lo = 0, hi = Cn;
        while (lo < hi) {
            const int mid = (lo + hi) >> 1;
            if (stS[mid] < Lq) lo = mid + 1; else hi = mid;
        }
        lo7[q] = lo;
    }
    Lv[4] = __shfl_down(Lv[0], 1, 64);  lo7[4] = __shfl_down(lo7[0], 1, 64);
    Lv[5] = __shfl_down(Lv[1], 1, 64);  lo7[5] = __shfl_down(lo7[1], 1, 64);
    Lv[6] = __shfl_down(Lv[2], 1, 64);  lo7[6] = __shfl_down(lo7[2], 1, 64);
    if ((tid & 63) == 63) {
        #pragma unroll
        for (int q = GPT; q < GPT + 3; ++q) {
            const int px = p4 + q;
            const float Lq = (px < HW) ? Lp[px] : 0.f;
            Lv[q] = Lq;
            int lo = 0, hi = Cn;
            while (lo < hi) {
                const int mid = (lo + hi) >> 1;
                if (stS[mid] < Lq) lo = mid + 1; else hi = mid;
            }
            lo7[q] = lo;
        }
    }

    float* const Pb = Pout + ((size_t)sb * Cn + (size_t)og * 4) * HW;

    if (p4 + GPT + 3 <= HW) {
        {   f32x4 v = f32x4{pwl(sab[0 * 66 + lo7[0]], Lv[0]),
                            pwl(sab[0 * 66 + lo7[1]], Lv[1]),
                            pwl(sab[0 * 66 + lo7[2]], Lv[2]),
                            pwl(sab[0 * 66 + lo7[3]], Lv[3])};
            *(f32x4*)(Pb + p4) = v; }
        {   f32x4 v = f32x4{pwl(sab[1 * 66 + lo7[3]], Lv[3]),
                            pwl(sab[1 * 66 + lo7[4]], Lv[4]),
                            pwl(sab[1 * 66 + lo7[5]], Lv[5]),
                            pwl(sab[1 * 66 + lo7[6]], Lv[6])};
            *(f32x4*)(Pb + (size_t)HW + p4 + 3) = v; }
        {   f32x4 v = f32x4{pwl(sab[2 * 66 + lo7[2]], Lv[2]),
                            pwl(sab[2 * 66 + lo7[3]], Lv[3]),
                            pwl(sab[2 * 66 + lo7[4]], Lv[4]),
                            pwl(sab[2 * 66 + lo7[5]], Lv[5])};
            *(f32x4*)(Pb + 2 * (size_t)HW + p4 + 2) = v; }
        {   f32x4 v = f32x4{pwl(sab[3 * 66 + lo7[1]], Lv[1]),
                            pwl(sab[3 * 66 + lo7[2]], Lv[2]),
                            pwl(sab[3 * 66 + lo7[3]], Lv[3]),
                            pwl(sab[3 * 66 + lo7[4]], Lv[4])};
            *(f32x4*)(Pb + 3 * (size_t)HW + p4 + 1) = v; }
        if (p4 == 0) {
            Pb[1 * (size_t)HW + 0] = pwl(sab[1 * 66 + lo7[0]], Lv[0]);
            Pb[1 * (size_t)HW + 1] = pwl(sab[1 * 66 + lo7[1]], Lv[1]);
            Pb[1 * (size_t)HW + 2] = pwl(sab[1 * 66 + lo7[2]], Lv[2]);
            Pb[2 * (size_t)HW + 0] = pwl(sab[2 * 66 + lo7[0]], Lv[0]);
            Pb[2 * (size_t)HW + 1] = pwl(sab[2 * 66 + lo7[1]], Lv[1]);
            Pb[3 * (size_t)HW + 0] = pwl(sab[3 * 66 + lo7[0]], Lv[0]);
        }
    } else {
        #pragma unroll
        for (int q = 0; q < GPT; ++q) {
            const int px = p4 + q;
            if (px >= HW) break;
            const float Lq = Lv[q];
            const int   r  = lo7[q];
            Pb[0 * (size_t)HW + px] = pwl(sab[0 * 66 + r], Lq);
            Pb[1 * (size_t)HW + px] = pwl(sab[1 * 66 + r], Lq);
            Pb[2 * (size_t)HW + px] = pwl(sab[2 * 66 + r], Lq);
            Pb[3 * (size_t)HW + px] = pwl(sab[3 * 66 + r], Lq);
        }
    }
}

extern "C" void kernel_launch(void* const* d_in, const int* in_sizes, int n_in,
                              void* d_out, int out_size, void* d_ws, size_t ws_size,
                              hipStream_t stream) {
    const float* x  = (const float*)d_in[0];
    const float* lp = (const float*)d_in[1];
    const float* hp = (const float*)d_in[2];
    const float* w1 = (const float*)d_in[3];
    const float* w2 = (const float*)d_in[4];
    const float* g1 = (const float*)d_in[5];
    const float* b1 = (const float*)d_in[6];
    const float* m1 = (const float*)d_in[7];
    const float* v1 = (const float*)d_in[8];
    const float* g2 = (const float*)d_in[9];
    const float* b2 = (const float*)d_in[10];
    const float* m2 = (const float*)d_in[11];
    const float* v2 = (const float*)d_in[12];

    float* out  = (float*)d_out;
    float* Lout = out;                  // [5,8,1,257,257]
    float* Hout = out + TOTPIX;         // [5,8,1,257,257]
    float* Pout = out + 2 * TOTPIX;     // [5,8,64,257,257]
    float* ws   = (float*)d_ws;

    precompute_kernel<<<Sn, Cn, 0, stream>>>(w1, w2, g1, b1, m1, v1,
                                             g2, b2, m2, v2, ws);

    dim3 grid1(NCHUNK, Bn, Sn);         // 65 x 8 x 5

    if (ws_size >= WS_NEED) {
        float* lrws = ws + LR_OFF;
        dwt_kernel<true><<<grid1, TPB, 0, stream>>>(x, lp, hp, ws,
                                                    Lout, Hout, lrws);
        pstore_flat<<<dim3(NBLK2), TPB, 0, stream>>>(ws, lrws, Pout);
    } else {
        dwt_kernel<false><<<grid1, TPB, 0, stream>>>(x, lp, hp, ws,
                                                     Lout, Hout, nullptr);
        dim3 grid2(NCHUNK, Cn / 4, Sn * Bn);
        pstore_v5<<<grid2, TPB, 0, stream>>>(Lout, ws, Pout);
    }
}

// Round 7
// 733.130 us; speedup vs baseline: 1.0898x; 1.0045x over previous
//
#include <hip/hip_runtime.h>
#include <math.h>

#define EPSF 1e-5f

constexpr int Sn = 5, Bn = 8, Hin = 512, Win = 512, Cn = 64;
constexpr int HO = 257, WO = 257;
constexpr int HW = HO * WO;           // 66049  (== 1 mod 4)
constexpr int NPIX = Bn * HW;         // 528392
constexpr int TOTPIX = Sn * NPIX;     // 2641960
constexpr int NSB = Sn * Bn;          // 40 (s,b) planes
constexpr int HWP = (HW + 3) & ~3;    // 66052, padded plane

// Output sections (floats): [L | H | P]
constexpr unsigned U_TOTPIX = (unsigned)TOTPIX;            //  2,641,960
constexpr unsigned U_TWOT   = 2u * U_TOTPIX;               //  5,283,920
constexpr unsigned PTOTu    = (unsigned)((long)NSB * Cn * HW);  // 169,085,440
constexpr unsigned U_TOT    = U_TWOT + PTOTu;              // 174,369,360

// Workspace layout (floats):
//   [0, 5*WSF)            : per-scale tables (64 breakpoints + ab[64][66] float2)
//   [LR_OFF, +NSB*HWP*2)  : (L, r) float2 per (sb, px)
//   [H_OFF,  +NSB*HWP)    : H per (sb, px)
constexpr int    WSF    = 64 + Cn * 66 * 2;                   // 8512
constexpr size_t LR_OFF = (size_t)Sn * WSF;                   // 42560
constexpr size_t H_OFF  = LR_OFF + (size_t)NSB * HWP * 2;
constexpr size_t WS_NEED = (H_OFF + (size_t)NSB * HWP) * 4;   // ~31.9 MB

typedef float f32x4 __attribute__((ext_vector_type(4)));
typedef f32x4 f32x4u __attribute__((aligned(8)));   // 8B-aligned vector loads

// ---------------------------------------------------------------------------
// Precompute: piecewise-linear table of the scalar->64ch MLP (unchanged).
// ---------------------------------------------------------------------------
__global__ __launch_bounds__(64) void precompute_kernel(
    const float* __restrict__ w1, const float* __restrict__ w2,
    const float* __restrict__ g1, const float* __restrict__ b1,
    const float* __restrict__ m1, const float* __restrict__ v1,
    const float* __restrict__ g2, const float* __restrict__ b2,
    const float* __restrict__ m2, const float* __restrict__ v2,
    float* __restrict__ ws) {
    int s = blockIdx.x;
    int c = threadIdx.x;
    __shared__ float sa1[Cn], st1[Cn], stc[Cn], stS[Cn];
    __shared__ int   scS[Cn];

    int idx = s * Cn + c;
    float sc1 = g1[idx] / sqrtf(v1[idx] + EPSF);
    float a1  = sc1 * w1[idx];                 // w1 shape (S,C,1)
    float t1  = b1[idx] - m1[idx] * sc1;
    sa1[c] = a1;
    st1[c] = t1;
    float tc = (a1 != 0.f) ? (-t1 / a1) : INFINITY;
    stc[c] = tc;
    __syncthreads();

    int rk = 0;
    for (int c2 = 0; c2 < Cn; c2++) {
        float t = stc[c2];
        rk += (t < tc) || (t == tc && c2 < c);
    }
    stS[rk] = tc;
    scS[rk] = c;
    __syncthreads();

    float* wss = ws + (size_t)s * WSF;
    wss[c] = stS[c];

    int o = c;
    float sc2 = g2[idx] / sqrtf(v2[idx] + EPSF);
    float t2o = b2[idx] - m2[idx] * sc2;
    const float* w2row = w2 + ((size_t)s * Cn + o) * Cn;

    float alpha = 0.f, beta = t2o;
    for (int cc = 0; cc < Cn; cc++) {
        float a = sa1[cc];
        bool act = (a < 0.f) || (a == 0.f && st1[cc] > 0.f);
        if (act) {
            float wf = sc2 * w2row[cc];
            alpha = fmaf(wf, a, alpha);
            beta  = fmaf(wf, st1[cc], beta);
        }
    }
    float2* abrow = (float2*)(wss + Cn);
    abrow[o * 66 + 0] = make_float2(alpha, beta);

    for (int r = 1; r <= Cn; r++) {
        int cc = scS[r - 1];
        float a = sa1[cc];
        if (a != 0.f) {
            float wf = sc2 * w2row[cc];
            float sgn = (a > 0.f) ? 1.f : -1.f;
            alpha = fmaf(sgn * wf, a, alpha);
            beta  = fmaf(sgn * wf, st1[cc], beta);
        }
        abrow[o * 66 + r] = make_float2(alpha, beta);
    }
}

// ---------------------------------------------------------------------------
// Shared helpers
// ---------------------------------------------------------------------------
constexpr int GPT = 4;
constexpr int TPB = 256;
constexpr int PIXPB = TPB * GPT;                  // 1024
constexpr int NCHUNK = (HW + PIXPB - 1) / PIXPB;  // 65

__device__ __forceinline__ float pwl(const float2 ab, float v) {
    return fmaxf(fmaf(ab.x, v, ab.y), 0.f);
}

__device__ __forceinline__ void dwt_lh(
    const float* __restrict__ xb, int i, int j,
    float l0, float l1, float h0, float h1,
    float& Lq, float& Hq) {
    const int r0 = 2 * i - 1, r1 = 2 * i;
    const int c0 = 2 * j - 1, c1 = 2 * j;
    const float x00 = (r0 >= 0 && r0 < Hin && c0 >= 0 ) ? xb[r0 * Win + c0] : 0.f;
    const float x01 = (r0 >= 0 && r0 < Hin && c1 < Win) ? xb[r0 * Win + c1] : 0.f;
    const float x10 = (r1 < Hin && c0 >= 0 )            ? xb[r1 * Win + c0] : 0.f;
    const float x11 = (r1 < Hin && c1 < Win)            ? xb[r1 * Win + c1] : 0.f;
    Lq = l0 * (l0 * x00 + l1 * x01) + l1 * (l0 * x10 + l1 * x11);
    Hq = h0 * (h0 * x00 + h1 * x01) + h1 * (h0 * x10 + h1 * x11);
}

// ---------------------------------------------------------------------------
// Pass 1 (primary): DWT + search -> ws only. No halo, no shfl, no phase
// switch: all ws stores are naturally aligned (HWP padded planes).
// ---------------------------------------------------------------------------
__global__ __launch_bounds__(TPB) void dwt_pack(
    const float* __restrict__ x,
    const float* __restrict__ lp, const float* __restrict__ hp,
    const float* __restrict__ ws_tab,
    float* __restrict__ lrws, float* __restrict__ hws) {
    __shared__ float stS[Cn];
    const int tid = threadIdx.x;
    const int b = blockIdx.y, s = blockIdx.z;
    if (tid < Cn) stS[tid] = ws_tab[(size_t)s * WSF + tid];
    __syncthreads();

    const int pbase = (blockIdx.x * TPB + tid) * GPT;
    if (pbase >= HW) return;

    const float l0 = lp[2 * s], l1 = lp[2 * s + 1];
    const float h0 = hp[2 * s], h1 = hp[2 * s + 1];
    const float* xb = x + (size_t)b * (Hin * Win);

    float Lv[GPT], Hv[GPT];
    int   rr[GPT];

    int i = pbase / WO;
    int j = pbase - i * WO;
    #pragma unroll
    for (int q = 0; q < GPT; ++q) {
        if (pbase + q < HW) {
            dwt_lh(xb, i, j, l0, l1, h0, h1, Lv[q], Hv[q]);
            int lo = 0, hi = Cn;
            while (lo < hi) {
                const int mid = (lo + hi) >> 1;
                if (stS[mid] < Lv[q]) lo = mid + 1; else hi = mid;
            }
            rr[q] = lo;
        } else { Lv[q] = 0.f; Hv[q] = 0.f; rr[q] = 0; }
        if (++j == WO) { j = 0; ++i; }
    }

    const int sb = s * Bn + b;
    float2* lr = (float2*)lrws + (size_t)sb * HWP + pbase;
    float*  hp_ = hws + (size_t)sb * HWP + pbase;

    if (pbase + GPT <= HW) {
        f32x4 p01 = f32x4{Lv[0], (float)rr[0], Lv[1], (float)rr[1]};
        f32x4 p23 = f32x4{Lv[2], (float)rr[2], Lv[3], (float)rr[3]};
        *(f32x4*)(lr)     = p01;      // 16B aligned: pbase%4==0, HWP%4==0
        *(f32x4*)(lr + 2) = p23;
        *(f32x4*)(hp_)    = f32x4{Hv[0], Hv[1], Hv[2], Hv[3]};
    } else {
        #pragma unroll
        for (int q = 0; q < GPT; ++q) {
            if (pbase + q < HW) {
                lr[q]  = make_float2(Lv[q], (float)rr[q]);
                hp_[q] = Hv[q];
            }
        }
    }
}

// ---------------------------------------------------------------------------
// Pass 2 (primary): the ENTIRE 697 MB output as one flat NT ramp.
// Blocks specialize by section; <=3 boundary blocks take the scalar path.
// ---------------------------------------------------------------------------
constexpr int EPB = TPB * 16;                               // 4096 elems/block
constexpr unsigned NBLK2 = (U_TOT + EPB - 1) / EPB;         // 42572

__global__ __launch_bounds__(TPB) void store_flat(
    const float* __restrict__ ws_tab,
    const float* __restrict__ lrws,
    const float* __restrict__ hws,
    float* __restrict__ out) {
    __shared__ float2 tabs[2][66];

    const int tid = threadIdx.x;
    const unsigned base = (unsigned)blockIdx.x * (unsigned)EPB;
    const float2* LR = (const float2*)lrws;

    if (base + EPB <= U_TOTPIX) {
        // ---------------- pure L section: copy LR.x flat -------------------
        #pragma unroll
        for (int k = 0; k < 4; ++k) {
            const unsigned f = base + (unsigned)k * (TPB * 4u) + (unsigned)tid * 4u;
            const unsigned sb  = f / (unsigned)HW;
            const unsigned px0 = f - sb * (unsigned)HW;
            if (px0 <= (unsigned)(HW - 4)) {
                const float2* lr = LR + (size_t)sb * HWP + px0;
                const f32x4u v01 = *(const f32x4u*)(lr);      // (L0,r0,L1,r1)
                const f32x4u v23 = *(const f32x4u*)(lr + 2);
                f32x4 v; v.x = v01.x; v.y = v01.z; v.z = v23.x; v.w = v23.z;
                __builtin_nontemporal_store(v, (f32x4*)(out + f));
            } else {
                #pragma unroll
                for (int e = 0; e < 4; ++e) {
                    const unsigned fe = f + (unsigned)e;
                    const unsigned s2 = fe / (unsigned)HW;
                    const unsigned px = fe - s2 * (unsigned)HW;
                    out[fe] = LR[(size_t)s2 * HWP + px].x;
                }
            }
        }
        return;
    }
    if (base >= U_TOTPIX && base + EPB <= U_TWOT) {
        // ---------------- pure H section: copy hws flat --------------------
        #pragma unroll
        for (int k = 0; k < 4; ++k) {
            const unsigned f = base + (unsigned)k * (TPB * 4u) + (unsigned)tid * 4u;
            const unsigned g = f - U_TOTPIX;
            const unsigned sb  = g / (unsigned)HW;
            const unsigned px0 = g - sb * (unsigned)HW;
            if (px0 <= (unsigned)(HW - 4)) {
                const float* hp_ = hws + (size_t)sb * HWP + px0;
                f32x4 v; v.x = hp_[0]; v.y = hp_[1]; v.z = hp_[2]; v.w = hp_[3];
                __builtin_nontemporal_store(v, (f32x4*)(out + f));
            } else {
                #pragma unroll
                for (int e = 0; e < 4; ++e) {
                    const unsigned ge = g + (unsigned)e;
                    const unsigned s2 = ge / (unsigned)HW;
                    const unsigned px = ge - s2 * (unsigned)HW;
                    out[U_TOTPIX + ge] = hws[(size_t)s2 * HWP + px];
                }
            }
        }
        return;
    }
    if (base >= U_TWOT && base + EPB <= U_TOT) {
        // ---------------- pure P section -----------------------------------
        const unsigned qbase = base - U_TWOT;
        const unsigned plane_first = qbase / (unsigned)HW;
        const unsigned plane_last  = (qbase + (unsigned)(EPB - 1)) / (unsigned)HW;
        if (tid < 132) {
            const int slot = (tid >= 66);
            const int idx  = slot ? tid - 66 : tid;
            const unsigned pl = slot ? plane_last : plane_first;
            const int s = (int)(pl >> 9);         // plane = (s*8+b)*64 + o
            const int o = (int)(pl & 63u);
            const float2* row =
                (const float2*)(ws_tab + (size_t)s * WSF + Cn) + (size_t)o * 66;
            tabs[slot][idx] = row[idx];
        }
        __syncthreads();

        #pragma unroll
        for (int k = 0; k < 4; ++k) {
            const unsigned q = qbase + (unsigned)k * (TPB * 4u) + (unsigned)tid * 4u;
            const unsigned plane = q / (unsigned)HW;
            const unsigned px0   = q - plane * (unsigned)HW;
            const int row = (plane != plane_first);
            if (px0 <= (unsigned)(HW - 4)) {
                const float2* lr = LR + (size_t)(plane >> 6) * HWP + px0;
                const f32x4u v01 = *(const f32x4u*)(lr);
                const f32x4u v23 = *(const f32x4u*)(lr + 2);
                const float2 ab0 = tabs[row][(int)v01.y];
                const float2 ab1 = tabs[row][(int)v01.w];
                const float2 ab2 = tabs[row][(int)v23.y];
                const float2 ab3 = tabs[row][(int)v23.w];
                f32x4 v;
                v.x = pwl(ab0, v01.x);
                v.y = pwl(ab1, v01.z);
                v.z = pwl(ab2, v23.x);
                v.w = pwl(ab3, v23.z);
                __builtin_nontemporal_store(v, (f32x4*)(out + U_TWOT + q));
            } else {
                #pragma unroll
                for (int e = 0; e < 4; ++e) {
                    const unsigned qe = q + (unsigned)e;
                    const unsigned pl = qe / (unsigned)HW;
                    const unsigned px = qe - pl * (unsigned)HW;
                    const int rw = (pl != plane_first);
                    const float2 lrv = LR[(size_t)(pl >> 6) * HWP + px];
                    const float2 ab  = tabs[rw][(int)lrv.y];
                    out[U_TWOT + qe] = pwl(ab, lrv.x);
                }
            }
        }
        return;
    }
    // ---------------- boundary blocks (<=3): scalar full logic -------------
    for (int k = 0; k < 16; ++k) {
        const unsigned f = base + (unsigned)k * (unsigned)TPB + (unsigned)tid;
        if (f >= U_TOT) return;
        if (f < U_TOTPIX) {
            const unsigned sb = f / (unsigned)HW;
            const unsigned px = f - sb * (unsigned)HW;
            out[f] = LR[(size_t)sb * HWP + px].x;
        } else if (f < U_TWOT) {
            const unsigned g  = f - U_TOTPIX;
            const unsigned sb = g / (unsigned)HW;
            const unsigned px = g - sb * (unsigned)HW;
            out[f] = hws[(size_t)sb * HWP + px];
        } else {
            const unsigned q  = f - U_TWOT;
            const unsigned pl = q / (unsigned)HW;
            const unsigned px = q - pl * (unsigned)HW;
            const int s = (int)(pl >> 9);
            const int o = (int)(pl & 63u);
            const float2 lrv = LR[(size_t)(pl >> 6) * HWP + px];
            const float2 ab  = ((const float2*)(ws_tab + (size_t)s * WSF + Cn))
                                   [(size_t)o * 66 + (int)lrv.y];
            out[f] = pwl(ab, lrv.x);
        }
    }
}

// ---------------------------------------------------------------------------
// Fallback path (verified v5/v6): dwt with halo writes L/H to out; pstore_v5.
// Used only if ws_size < WS_NEED (tables-only, 170 KB).
// ---------------------------------------------------------------------------
__global__ __launch_bounds__(TPB) void dwt_halo(
    const float* __restrict__ x,
    const float* __restrict__ lp, const float* __restrict__ hp,
    float* __restrict__ Lout, float* __restrict__ Hout) {
    const int tid = threadIdx.x;
    const int b = blockIdx.y, s = blockIdx.z;

    const float l0 = lp[2 * s], l1 = lp[2 * s + 1];
    const float h0 = hp[2 * s], h1 = hp[2 * s + 1];
    const float* xb = x + (size_t)b * (Hin * Win);

    const int pbase = (blockIdx.x * TPB + tid) * GPT;
    if (pbase >= HW) return;

    float Lv[GPT + 3], Hv[GPT + 3];
    int i = pbase / WO;
    int j = pbase - i * WO;
    #pragma unroll
    for (int q = 0; q < GPT; ++q) {
        dwt_lh(xb, i, j, l0, l1, h0, h1, Lv[q], Hv[q]);
        if (++j == WO) { j = 0; ++i; }
    }
    Lv[4] = __shfl_down(Lv[0], 1, 64);  Hv[4] = __shfl_down(Hv[0], 1, 64);
    Lv[5] = __shfl_down(Lv[1], 1, 64);  Hv[5] = __shfl_down(Hv[1], 1, 64);
    Lv[6] = __shfl_down(Lv[2], 1, 64);  Hv[6] = __shfl_down(Hv[2], 1, 64);
    if ((tid & 63) == 63) {
        #pragma unroll
        for (int q = GPT; q < GPT + 3; ++q) {
            dwt_lh(xb, i, j, l0, l1, h0, h1, Lv[q], Hv[q]);
            if (++j == WO) { j = 0; ++i; }
        }
    }

    const int sb = s * Bn + b;
    const size_t lb = (size_t)sb * HW + pbase;
    const int dlt = (4 - (sb & 3)) & 3;
    const bool fast = (pbase + GPT + 3 <= HW);

    if (fast) {
        f32x4 l4, h4;
        switch (dlt) {
            case 0:  l4 = f32x4{Lv[0], Lv[1], Lv[2], Lv[3]};
                     h4 = f32x4{Hv[0], Hv[1], Hv[2], Hv[3]}; break;
            case 1:  l4 = f32x4{Lv[1], Lv[2], Lv[3], Lv[4]};
                     h4 = f32x4{Hv[1], Hv[2], Hv[3], Hv[4]}; break;
            case 2:  l4 = f32x4{Lv[2], Lv[3], Lv[4], Lv[5]};
                     h4 = f32x4{Hv[2], Hv[3], Hv[4], Hv[5]}; break;
            default: l4 = f32x4{Lv[3], Lv[4], Lv[5], Lv[6]};
                     h4 = f32x4{Hv[3], Hv[4], Hv[5], Hv[6]}; break;
        }
        *(f32x4*)(Lout + lb + dlt) = l4;
        __builtin_nontemporal_store(h4, (f32x4*)(Hout + lb + dlt));
        if (pbase == 0) {
            if (dlt > 0) { Lout[lb + 0] = Lv[0]; Hout[lb + 0] = Hv[0]; }
            if (dlt > 1) { Lout[lb + 1] = Lv[1]; Hout[lb + 1] = Hv[1]; }
            if (dlt > 2) { Lout[lb + 2] = Lv[2]; Hout[lb + 2] = Hv[2]; }
        }
    } else {
        #pragma unroll
        for (int q = 0; q < GPT; ++q) {
            if (pbase + q < HW) {
                Lout[lb + q] = Lv[q];
                Hout[lb + q] = Hv[q];
            }
        }
    }
}

__global__ __launch_bounds__(TPB) void pstore_v5(
    const float* __restrict__ Lin,
    const float* __restrict__ ws,
    float* __restrict__ Pout) {
    __shared__ float  stS[Cn];
    __shared__ float2 sab[4 * 66];

    const int tid = threadIdx.x;
    const int og  = blockIdx.y;
    const int sb  = blockIdx.z;
    const int s   = sb >> 3;

    const float* wss = ws + (size_t)s * WSF;
    if (tid < Cn) stS[tid] = wss[tid];
    const float2* abg = (const float2*)(wss + Cn) + (size_t)og * 4 * 66;
    for (int t = tid; t < 4 * 66; t += TPB) sab[t] = abg[t];
    __syncthreads();

    const int p4 = (blockIdx.x * TPB + tid) * GPT;
    const float* Lp = Lin + (size_t)sb * HW;

    float Lv[GPT + 3];
    int   lo7[GPT + 3];

    #pragma unroll
    for (int q = 0; q < GPT; ++q) {
        const int px = p4 + q;
        const float Lq = (px < HW) ? Lp[px] : 0.f;
        Lv[q] = Lq;
        int lo = 0, hi = Cn;
        while (lo < hi) {
            const int mid = (lo + hi) >> 1;
            if (stS[mid] < Lq) lo = mid + 1; else hi = mid;
        }
        lo7[q] = lo;
    }
    Lv[4] = __shfl_down(Lv[0], 1, 64);  lo7[4] = __shfl_down(lo7[0], 1, 64);
    Lv[5] = __shfl_down(Lv[1], 1, 64);  lo7[5] = __shfl_down(lo7[1], 1, 64);
    Lv[6] = __shfl_down(Lv[2], 1, 64);  lo7[6] = __shfl_down(lo7[2], 1, 64);
    if ((tid & 63) == 63) {
        #pragma unroll
        for (int q = GPT; q < GPT + 3; ++q) {
            const int px = p4 + q;
            const float Lq = (px < HW) ? Lp[px] : 0.f;
            Lv[q] = Lq;
            int lo = 0, hi = Cn;
            while (lo < hi) {
                const int mid = (lo + hi) >> 1;
                if (stS[mid] < Lq) lo = mid + 1; else hi = mid;
            }
            lo7[q] = lo;
        }
    }

    float* const Pb = Pout + ((size_t)sb * Cn + (size_t)og * 4) * HW;

    if (p4 + GPT + 3 <= HW) {
        {   f32x4 v = f32x4{pwl(sab[0 * 66 + lo7[0]], Lv[0]),
                            pwl(sab[0 * 66 + lo7[1]], Lv[1]),
                            pwl(sab[0 * 66 + lo7[2]], Lv[2]),
                            pwl(sab[0 * 66 + lo7[3]], Lv[3])};
            *(f32x4*)(Pb + p4) = v; }
        {   f32x4 v = f32x4{pwl(sab[1 * 66 + lo7[3]], Lv[3]),
                            pwl(sab[1 * 66 + lo7[4]], Lv[4]),
                            pwl(sab[1 * 66 + lo7[5]], Lv[5]),
                            pwl(sab[1 * 66 + lo7[6]], Lv[6])};
            *(f32x4*)(Pb + (size_t)HW + p4 + 3) = v; }
        {   f32x4 v = f32x4{pwl(sab[2 * 66 + lo7[2]], Lv[2]),
                            pwl(sab[2 * 66 + lo7[3]], Lv[3]),
                            pwl(sab[2 * 66 + lo7[4]], Lv[4]),
                            pwl(sab[2 * 66 + lo7[5]], Lv[5])};
            *(f32x4*)(Pb + 2 * (size_t)HW + p4 + 2) = v; }
        {   f32x4 v = f32x4{pwl(sab[3 * 66 + lo7[1]], Lv[1]),
                            pwl(sab[3 * 66 + lo7[2]], Lv[2]),
                            pwl(sab[3 * 66 + lo7[3]], Lv[3]),
                            pwl(sab[3 * 66 + lo7[4]], Lv[4])};
            *(f32x4*)(Pb + 3 * (size_t)HW + p4 + 1) = v; }
        if (p4 == 0) {
            Pb[1 * (size_t)HW + 0] = pwl(sab[1 * 66 + lo7[0]], Lv[0]);
            Pb[1 * (size_t)HW + 1] = pwl(sab[1 * 66 + lo7[1]], Lv[1]);
            Pb[1 * (size_t)HW + 2] = pwl(sab[1 * 66 + lo7[2]], Lv[2]);
            Pb[2 * (size_t)HW + 0] = pwl(sab[2 * 66 + lo7[0]], Lv[0]);
            Pb[2 * (size_t)HW + 1] = pwl(sab[2 * 66 + lo7[1]], Lv[1]);
            Pb[3 * (size_t)HW + 0] = pwl(sab[3 * 66 + lo7[0]], Lv[0]);
        }
    } else {
        #pragma unroll
        for (int q = 0; q < GPT; ++q) {
            const int px = p4 + q;
            if (px >= HW) break;
            const float Lq = Lv[q];
            const int   r  = lo7[q];
            Pb[0 * (size_t)HW + px] = pwl(sab[0 * 66 + r], Lq);
            Pb[1 * (size_t)HW + px] = pwl(sab[1 * 66 + r], Lq);
            Pb[2 * (size_t)HW + px] = pwl(sab[2 * 66 + r], Lq);
            Pb[3 * (size_t)HW + px] = pwl(sab[3 * 66 + r], Lq);
        }
    }
}

extern "C" void kernel_launch(void* const* d_in, const int* in_sizes, int n_in,
                              void* d_out, int out_size, void* d_ws, size_t ws_size,
                              hipStream_t stream) {
    const float* x  = (const float*)d_in[0];
    const float* lp = (const float*)d_in[1];
    const float* hp = (const float*)d_in[2];
    const float* w1 = (const float*)d_in[3];
    const float* w2 = (const float*)d_in[4];
    const float* g1 = (const float*)d_in[5];
    const float* b1 = (const float*)d_in[6];
    const float* m1 = (const float*)d_in[7];
    const float* v1 = (const float*)d_in[8];
    const float* g2 = (const float*)d_in[9];
    const float* b2 = (const float*)d_in[10];
    const float* m2 = (const float*)d_in[11];
    const float* v2 = (const float*)d_in[12];

    float* out  = (float*)d_out;
    float* Lout = out;                  // [5,8,1,257,257]
    float* Hout = out + TOTPIX;         // [5,8,1,257,257]
    float* Pout = out + 2 * TOTPIX;     // [5,8,64,257,257]
    float* ws   = (float*)d_ws;

    precompute_kernel<<<Sn, Cn, 0, stream>>>(w1, w2, g1, b1, m1, v1,
                                             g2, b2, m2, v2, ws);

    dim3 grid1(NCHUNK, Bn, Sn);         // 65 x 8 x 5

    if (ws_size >= WS_NEED) {
        float* lrws = ws + LR_OFF;
        float* hws  = ws + H_OFF;
        dwt_pack<<<grid1, TPB, 0, stream>>>(x, lp, hp, ws, lrws, hws);
        store_flat<<<dim3(NBLK2), TPB, 0, stream>>>(ws, lrws, hws, out);
    } else {
        dwt_halo<<<grid1, TPB, 0, stream>>>(x, lp, hp, Lout, Hout);
        dim3 grid2(NCHUNK, Cn / 4, Sn * Bn);
        pstore_v5<<<grid2, TPB, 0, stream>>>(Lout, ws, Pout);
    }
}